// Round 1
// baseline (248.392 us; speedup 1.0000x reference)
//
#include <hip/hip_runtime.h>

#define HDIM 8

// ---- fast device math (v_exp_f32 / v_rcp_f32) ----
__device__ __forceinline__ float ex2(float x) {
#if __has_builtin(__builtin_amdgcn_exp2f)
    return __builtin_amdgcn_exp2f(x);
#else
    return exp2f(x);
#endif
}
__device__ __forceinline__ float rcp(float x) {
#if __has_builtin(__builtin_amdgcn_rcpf)
    return __builtin_amdgcn_rcpf(x);
#else
    return 1.0f / x;
#endif
}

// sigmoid(s) = 1 / (1 + exp(-s)) = 1 / (1 + exp2(-s*log2e))
__device__ __forceinline__ float sigm(float s) {
    return rcp(1.0f + ex2(-1.4426950408889634f * s));
}
// tanh(u) = 1 - 2/(exp2(2u*log2e) + 1)
__device__ __forceinline__ float tanh_fast(float u) {
    return 1.0f - 2.0f * rcp(1.0f + ex2(2.8853900817779268f * u));
}

// One GRU element, 8 lanes cooperate (lane j owns hidden unit j and gate rows
// j, j+8, j+16). h[0..7] kept replicated in every lane's registers; after each
// step the new h_j is re-broadcast with width-8 shuffles (ds_swizzle).
template <int IN>
__device__ float gru_elem(const float* __restrict__ xbase, int t_stride_f, int T,
                          const float* __restrict__ Wih, const float* __restrict__ Whh,
                          const float* __restrict__ bih, const float* __restrict__ bhh,
                          int j)
{
    // recurrent weights for this lane's three gate rows
    float wr[HDIM], wz[HDIM], wn[HDIM];
#pragma unroll
    for (int k = 0; k < HDIM; ++k) {
        wr[k] = Whh[(j     ) * HDIM + k];
        wz[k] = Whh[(j +  8) * HDIM + k];
        wn[k] = Whh[(j + 16) * HDIM + k];
    }
    // input weights
    float uir[IN], uiz[IN], uin[IN];
#pragma unroll
    for (int i = 0; i < IN; ++i) {
        uir[i] = Wih[(j     ) * IN + i];
        uiz[i] = Wih[(j +  8) * IN + i];
        uin[i] = Wih[(j + 16) * IN + i];
    }
    const float br   = bih[j]      + bhh[j];
    const float bz   = bih[j +  8] + bhh[j + 8];
    const float bin_ = bih[j + 16];
    const float bhn  = bhh[j + 16];

    float h[HDIM];
#pragma unroll
    for (int k = 0; k < HDIM; ++k) h[k] = 0.0f;
    float hown = 0.0f;   // this lane's own h_j (avoids runtime-indexing h[])

    // current-step input (prefetched)
    float xcur[IN];
    {
        if constexpr (IN == 4) {
            float4 v = *reinterpret_cast<const float4*>(xbase);
            xcur[0] = v.x; xcur[1] = v.y; xcur[2] = v.z; xcur[3] = v.w;
        } else {
            float2 v = *reinterpret_cast<const float2*>(xbase);
            xcur[0] = v.x; xcur[1] = v.y;
        }
    }

    for (int t = 0; t < T; ++t) {
        // prefetch next step's input (independent of the h-chain)
        float xnxt[IN];
        if (t + 1 < T) {
            const float* nxt = xbase + (size_t)(t + 1) * t_stride_f;
            if constexpr (IN == 4) {
                float4 v = *reinterpret_cast<const float4*>(nxt);
                xnxt[0] = v.x; xnxt[1] = v.y; xnxt[2] = v.z; xnxt[3] = v.w;
            } else {
                float2 v = *reinterpret_cast<const float2*>(nxt);
                xnxt[0] = v.x; xnxt[1] = v.y;
            }
        } else {
#pragma unroll
            for (int i = 0; i < IN; ++i) xnxt[i] = 0.0f;
        }

        // input projections (off the recurrent chain)
        float ar = br, az = bz, an = bin_;
#pragma unroll
        for (int i = 0; i < IN; ++i) {
            ar += uir[i] * xcur[i];
            az += uiz[i] * xcur[i];
            an += uin[i] * xcur[i];
        }

        // recurrent matvec: three dot-8 products from replicated h
        float hr = 0.0f, hz = 0.0f, hn = bhn;
#pragma unroll
        for (int k = 0; k < HDIM; ++k) {
            hr += wr[k] * h[k];
            hz += wz[k] * h[k];
            hn += wn[k] * h[k];
        }

        float r = sigm(ar + hr);
        float z = sigm(az + hz);
        float n = tanh_fast(an + r * hn);    // bhh_n stays inside r*( ) per torch
        hown = n + z * (hown - n);           // (1-z)*n + z*h

        // redistribute h_new across the 8-lane group
#pragma unroll
        for (int k = 0; k < HDIM; ++k) h[k] = __shfl(hown, k, 8);

#pragma unroll
        for (int i = 0; i < IN; ++i) xcur[i] = xnxt[i];
    }
    return hown;
}

// block = 128 threads = 2 waves. wave 0: bbox GRU, wave 1: flow GRU, for the
// same 8 batch elements (8 lanes per element). Combine via LDS at the end.
__global__ __launch_bounds__(128)
void gru_fused_kernel(const float* __restrict__ bbox, const float* __restrict__ flow,
                      const float* __restrict__ Wih_b, const float* __restrict__ Whh_b,
                      const float* __restrict__ bih_b, const float* __restrict__ bhh_b,
                      const float* __restrict__ Wih_f, const float* __restrict__ Whh_f,
                      const float* __restrict__ bih_f, const float* __restrict__ bhh_f,
                      float* __restrict__ out, int T)
{
    const int tid  = threadIdx.x;
    const int wave = tid >> 6;
    const int lane = tid & 63;
    const int grp  = lane >> 3;     // element within wave (0..7)
    const int j    = lane & 7;      // hidden unit (0..7)
    const int e    = blockIdx.x * 8 + grp;

    __shared__ float sh[2][8][HDIM];

    float hT;
    if (wave == 0) {
        const float* xb = bbox + (size_t)e * T * 4;
        hT = gru_elem<4>(xb, 4, T, Wih_b, Whh_b, bih_b, bhh_b, j);
    } else {
        // flow[e, t, 2, 2, :] -> offset (e*T + t)*50 + 24, stride 50 floats
        const float* xf = flow + (size_t)e * T * 50 + 24;
        hT = gru_elem<2>(xf, 50, T, Wih_f, Whh_f, bih_f, bhh_f, j);
    }

    sh[wave][grp][j] = hT;
    __syncthreads();
    if (wave == 0) {
        out[(size_t)e * HDIM + j] = 0.5f * (sh[0][grp][j] + sh[1][grp][j]);
    }
}

extern "C" void kernel_launch(void* const* d_in, const int* in_sizes, int n_in,
                              void* d_out, int out_size, void* d_ws, size_t ws_size,
                              hipStream_t stream) {
    const float* bbox  = (const float*)d_in[0];
    const float* flow  = (const float*)d_in[1];
    const float* Wih_b = (const float*)d_in[2];
    const float* Whh_b = (const float*)d_in[3];
    const float* bih_b = (const float*)d_in[4];
    const float* bhh_b = (const float*)d_in[5];
    const float* Wih_f = (const float*)d_in[6];
    const float* Whh_f = (const float*)d_in[7];
    const float* bih_f = (const float*)d_in[8];
    const float* bhh_f = (const float*)d_in[9];
    float* out = (float*)d_out;

    const int B = out_size / HDIM;            // 1024
    const int T = in_sizes[0] / (4 * B);      // 512

    dim3 grid(B / 8), block(128);
    gru_fused_kernel<<<grid, block, 0, stream>>>(
        bbox, flow, Wih_b, Whh_b, bih_b, bhh_b,
        Wih_f, Whh_f, bih_f, bhh_f, out, T);
}

// Round 2
// 92.339 us; speedup vs baseline: 2.6900x; 2.6900x over previous
//
#include <hip/hip_runtime.h>

#define HDIM 8

// ---- fast device math (v_exp_f32 / v_rcp_f32) ----
__device__ __forceinline__ float ex2(float x) {
#if __has_builtin(__builtin_amdgcn_exp2f)
    return __builtin_amdgcn_exp2f(x);
#else
    return exp2f(x);
#endif
}
__device__ __forceinline__ float rcp(float x) {
#if __has_builtin(__builtin_amdgcn_rcpf)
    return __builtin_amdgcn_rcpf(x);
#else
    return 1.0f / x;
#endif
}

// Distributed-h GRU: 8 lanes per element, lane j owns hidden unit j only.
// Per step, 7 independent ds_bpermute (XOR pattern) deliver the other lanes'
// h values; weights are pre-permuted into XOR order (w[m] pairs with h_{j^m}).
// Gate pre-activations are prescaled by -log2e (r,z) / 2log2e (n) so the
// sigmoid/tanh need no multiply on the chain.
// Inputs are prefetched 8 steps deep; their projections are computed in bulk
// off the recurrent chain.
template <int IN>
__device__ float gru_elem(const float* __restrict__ xbase, int stride_f, int T,
                          const float* __restrict__ Wih, const float* __restrict__ Whh,
                          const float* __restrict__ bih, const float* __restrict__ bhh,
                          int j, int lane)
{
    const float NL2E = -1.4426950408889634f;  // -log2(e)
    const float L2E2 =  2.8853900817779268f;  //  2*log2(e)

    // recurrent weights in XOR order
    float wr[8], wz[8], wn[8];
#pragma unroll
    for (int m = 0; m < 8; ++m) {
        const int k = j ^ m;
        wr[m] = NL2E * Whh[(j     ) * HDIM + k];
        wz[m] = NL2E * Whh[(j +  8) * HDIM + k];
        wn[m] = L2E2 * Whh[(j + 16) * HDIM + k];
    }
    // input weights (prescaled)
    float uir[IN], uiz[IN], uin[IN];
#pragma unroll
    for (int i = 0; i < IN; ++i) {
        uir[i] = NL2E * Wih[(j     ) * IN + i];
        uiz[i] = NL2E * Wih[(j +  8) * IN + i];
        uin[i] = L2E2 * Wih[(j + 16) * IN + i];
    }
    const float br  = NL2E * (bih[j]     + bhh[j]);
    const float bz  = NL2E * (bih[j + 8] + bhh[j + 8]);
    const float bn  = L2E2 * bih[j + 16];
    const float bhn = L2E2 * bhh[j + 16];

    // precomputed bpermute byte-addresses for the 7 XOR partners
    int adr[7];
#pragma unroll
    for (int m = 1; m < 8; ++m) adr[m - 1] = ((lane ^ m) << 2);

    constexpr int U = 8;          // prefetch depth / unroll
    float xb[U][IN];              // staged inputs (single buffer, ping within block)
    float pr[U], pz[U], pn[U];    // prescaled input projections

    auto loadx = [&](int base) {
#pragma unroll
        for (int s = 0; s < U; ++s) {
            int idx = base + s; if (idx > T - 1) idx = T - 1;   // clamp (tail values unused)
            const float* p = xbase + (size_t)idx * stride_f;
            if constexpr (IN == 4) {
                float4 v = *reinterpret_cast<const float4*>(p);
                xb[s][0] = v.x; xb[s][1] = v.y; xb[s][2] = v.z; xb[s][3] = v.w;
            } else {
                float2 v = *reinterpret_cast<const float2*>(p);
                xb[s][0] = v.x; xb[s][1] = v.y;
            }
        }
    };
    auto proj = [&]() {
#pragma unroll
        for (int s = 0; s < U; ++s) {
            float a = br, b = bz, c = bn;
#pragma unroll
            for (int i = 0; i < IN; ++i) {
                a = fmaf(uir[i], xb[s][i], a);
                b = fmaf(uiz[i], xb[s][i], b);
                c = fmaf(uin[i], xb[s][i], c);
            }
            pr[s] = a; pz[s] = b; pn[s] = c;
        }
    };

    loadx(0);
    proj();
    float hj = 0.0f;

    for (int t0 = 0; t0 < T; t0 += U) {
        loadx(t0 + U);   // issue next-bank loads; consumed by proj() below
#pragma unroll
        for (int s = 0; s < U; ++s) {
            float hx[8];
            hx[0] = hj;
#pragma unroll
            for (int m = 1; m < 8; ++m)
                hx[m] = __int_as_float(
                    __builtin_amdgcn_ds_bpermute(adr[m - 1], __float_as_int(hj)));

            // 3-level tree dots (bias/proj folded into one branch)
            float sr = ((wr[0]*hx[0] + wr[1]*hx[1]) + (wr[2]*hx[2] + wr[3]*hx[3]))
                     + ((wr[4]*hx[4] + wr[5]*hx[5]) + (wr[6]*hx[6] + wr[7]*hx[7] + pr[s]));
            float sz = ((wz[0]*hx[0] + wz[1]*hx[1]) + (wz[2]*hx[2] + wz[3]*hx[3]))
                     + ((wz[4]*hx[4] + wz[5]*hx[5]) + (wz[6]*hx[6] + wz[7]*hx[7] + pz[s]));
            float sn = ((wn[0]*hx[0] + wn[1]*hx[1]) + (wn[2]*hx[2] + wn[3]*hx[3]))
                     + ((wn[4]*hx[4] + wn[5]*hx[5]) + (wn[6]*hx[6] + wn[7]*hx[7] + bhn));

            float r = rcp(1.0f + ex2(sr));               // sigmoid (prescaled arg)
            float z = rcp(1.0f + ex2(sz));
            float u = fmaf(r, sn, pn[s]);                // 2log2e*(an + r*hn)
            float n = fmaf(-2.0f, rcp(1.0f + ex2(u)), 1.0f);   // tanh
            hj = fmaf(z, hj - n, n);                     // (1-z)*n + z*h
        }
        proj();          // projections for next bank (vmcnt wait lands here)
    }
    return hj;
}

// block = 128 threads = 2 waves. wave 0: bbox GRU, wave 1: flow GRU, for the
// same 8 batch elements (8 lanes per element). Combine via LDS at the end.
__global__ __launch_bounds__(128)
void gru_fused_kernel(const float* __restrict__ bbox, const float* __restrict__ flow,
                      const float* __restrict__ Wih_b, const float* __restrict__ Whh_b,
                      const float* __restrict__ bih_b, const float* __restrict__ bhh_b,
                      const float* __restrict__ Wih_f, const float* __restrict__ Whh_f,
                      const float* __restrict__ bih_f, const float* __restrict__ bhh_f,
                      float* __restrict__ out, int T)
{
    const int tid  = threadIdx.x;
    const int wave = tid >> 6;
    const int lane = tid & 63;
    const int grp  = lane >> 3;     // element within wave (0..7)
    const int j    = lane & 7;      // hidden unit (0..7)
    const int e    = blockIdx.x * 8 + grp;

    __shared__ float sh[2][8][HDIM];

    float hT;
    if (wave == 0) {
        const float* xb = bbox + (size_t)e * T * 4;
        hT = gru_elem<4>(xb, 4, T, Wih_b, Whh_b, bih_b, bhh_b, j, lane);
    } else {
        // flow[e, t, 2, 2, :] -> offset (e*T + t)*50 + 24, stride 50 floats
        const float* xf = flow + (size_t)e * T * 50 + 24;
        hT = gru_elem<2>(xf, 50, T, Wih_f, Whh_f, bih_f, bhh_f, j, lane);
    }

    sh[wave][grp][j] = hT;
    __syncthreads();
    if (wave == 0) {
        out[(size_t)e * HDIM + j] = 0.5f * (sh[0][grp][j] + sh[1][grp][j]);
    }
}

extern "C" void kernel_launch(void* const* d_in, const int* in_sizes, int n_in,
                              void* d_out, int out_size, void* d_ws, size_t ws_size,
                              hipStream_t stream) {
    const float* bbox  = (const float*)d_in[0];
    const float* flow  = (const float*)d_in[1];
    const float* Wih_b = (const float*)d_in[2];
    const float* Whh_b = (const float*)d_in[3];
    const float* bih_b = (const float*)d_in[4];
    const float* bhh_b = (const float*)d_in[5];
    const float* Wih_f = (const float*)d_in[6];
    const float* Whh_f = (const float*)d_in[7];
    const float* bih_f = (const float*)d_in[8];
    const float* bhh_f = (const float*)d_in[9];
    float* out = (float*)d_out;

    const int B = out_size / HDIM;            // 1024
    const int T = in_sizes[0] / (4 * B);      // 512

    dim3 grid(B / 8), block(128);
    gru_fused_kernel<<<grid, block, 0, stream>>>(
        bbox, flow, Wih_b, Whh_b, bih_b, bhh_b,
        Wih_f, Whh_f, bih_f, bhh_f, out, T);
}

// Round 3
// 71.405 us; speedup vs baseline: 3.4786x; 1.2932x over previous
//
#include <hip/hip_runtime.h>

#define HDIM 8

// ---- fast device math (v_exp_f32 / v_rcp_f32) ----
__device__ __forceinline__ float ex2(float x) {
#if __has_builtin(__builtin_amdgcn_exp2f)
    return __builtin_amdgcn_exp2f(x);
#else
    return exp2f(x);
#endif
}
__device__ __forceinline__ float rcp(float x) {
#if __has_builtin(__builtin_amdgcn_rcpf)
    return __builtin_amdgcn_rcpf(x);
#else
    return 1.0f / x;
#endif
}

// v_mov_b32_dpp row_ror:N (N must be an immediate). 0x120+N is the ROW_ROR
// DPP ctrl encoding. row_mask=0xF bank_mask=0xF bound_ctrl=1 (no OOB lanes for
// full-row rotation, so bound_ctrl is irrelevant).
#define DPP_ROR(v, N)                                                        \
    __int_as_float(__builtin_amdgcn_update_dpp(                              \
        0, __float_as_int(v), 0x120 + (N), 0xF, 0xF, true))

// Distributed-h GRU, DPP edition.
// Lane mapping: each 16-lane DPP row holds TWO elements interleaved
// (element A on even lanes, element B on odd lanes); j = (lane&15)>>1 is the
// hidden unit this lane owns. row_ror:2m then rotates by m within each 8-lane
// parity class — a pure-VALU h all-gather (no LDS in the recurrent loop).
// Rotation direction is probed at runtime and folded into the weight gather.
template <int IN>
__device__ float gru_elem(const float* __restrict__ xbase, int stride_f, int T,
                          const float* __restrict__ Wih, const float* __restrict__ Whh,
                          const float* __restrict__ bih, const float* __restrict__ bhh,
                          int j)
{
    const float NL2E = -1.4426950408889634f;  // -log2(e)
    const float L2E2 =  2.8853900817779268f;  //  2*log2(e)

    // --- probe row_ror direction: partner of rotation 2 has unit (j +- 1)&7
    float nb = DPP_ROR((float)j, 2);
    const int dstep = (nb == (float)((j + 1) & 7)) ? 1 : 7;   // +1 or -1 mod 8

    // recurrent weights in rotation order: w[m] pairs with h_{(j + dstep*m)&7}
    float wr[8], wz[8], wn[8];
#pragma unroll
    for (int m = 0; m < 8; ++m) {
        const int k = (j + dstep * m) & 7;
        wr[m] = NL2E * Whh[(j     ) * HDIM + k];
        wz[m] = NL2E * Whh[(j +  8) * HDIM + k];
        wn[m] = L2E2 * Whh[(j + 16) * HDIM + k];
    }
    // input weights (prescaled)
    float uir[IN], uiz[IN], uin[IN];
#pragma unroll
    for (int i = 0; i < IN; ++i) {
        uir[i] = NL2E * Wih[(j     ) * IN + i];
        uiz[i] = NL2E * Wih[(j +  8) * IN + i];
        uin[i] = L2E2 * Wih[(j + 16) * IN + i];
    }
    const float br  = NL2E * (bih[j]     + bhh[j]);
    const float bz  = NL2E * (bih[j + 8] + bhh[j + 8]);
    const float bn  = L2E2 * bih[j + 16];
    const float bhn = L2E2 * bhh[j + 16];

    constexpr int U = 8;          // prefetch depth / unroll
    float xb[U][IN];              // staged inputs
    float pr[U], pz[U], pn[U];    // prescaled input projections

    auto loadx = [&](int base) {
#pragma unroll
        for (int s = 0; s < U; ++s) {
            int idx = base + s; if (idx > T - 1) idx = T - 1;   // clamp (tail unused)
            const float* p = xbase + (size_t)idx * stride_f;
            if constexpr (IN == 4) {
                float4 v = *reinterpret_cast<const float4*>(p);
                xb[s][0] = v.x; xb[s][1] = v.y; xb[s][2] = v.z; xb[s][3] = v.w;
            } else {
                float2 v = *reinterpret_cast<const float2*>(p);
                xb[s][0] = v.x; xb[s][1] = v.y;
            }
        }
    };
    auto proj = [&]() {
#pragma unroll
        for (int s = 0; s < U; ++s) {
            float a = br, b = bz, c = bn;
#pragma unroll
            for (int i = 0; i < IN; ++i) {
                a = fmaf(uir[i], xb[s][i], a);
                b = fmaf(uiz[i], xb[s][i], b);
                c = fmaf(uin[i], xb[s][i], c);
            }
            pr[s] = a; pz[s] = b; pn[s] = c;
        }
    };

    loadx(0);
    proj();
    float hj = 0.0f;

    for (int t0 = 0; t0 < T; t0 += U) {
        loadx(t0 + U);   // issue next-bank loads; consumed by proj() below
#pragma unroll
        for (int s = 0; s < U; ++s) {
            // h all-gather: 7 DPP row-rotations (VALU, no LDS)
            const float hx0 = hj;
            const float hx1 = DPP_ROR(hj,  2);
            const float hx2 = DPP_ROR(hj,  4);
            const float hx3 = DPP_ROR(hj,  6);
            const float hx4 = DPP_ROR(hj,  8);
            const float hx5 = DPP_ROR(hj, 10);
            const float hx6 = DPP_ROR(hj, 12);
            const float hx7 = DPP_ROR(hj, 14);

            // two 4-FMA chains per row, then one add (proj/bias folded in)
            float ra = fmaf(wr[3], hx3, fmaf(wr[2], hx2, fmaf(wr[1], hx1, fmaf(wr[0], hx0, pr[s]))));
            float rb = fmaf(wr[7], hx7, fmaf(wr[6], hx6, fmaf(wr[5], hx5, wr[4] * hx4)));
            float za = fmaf(wz[3], hx3, fmaf(wz[2], hx2, fmaf(wz[1], hx1, fmaf(wz[0], hx0, pz[s]))));
            float zb = fmaf(wz[7], hx7, fmaf(wz[6], hx6, fmaf(wz[5], hx5, wz[4] * hx4)));
            float na = fmaf(wn[3], hx3, fmaf(wn[2], hx2, fmaf(wn[1], hx1, fmaf(wn[0], hx0, bhn))));
            float nb2 = fmaf(wn[7], hx7, fmaf(wn[6], hx6, fmaf(wn[5], hx5, wn[4] * hx4)));
            float sr = ra + rb;
            float sz = za + zb;
            float sn = na + nb2;

            float r = rcp(1.0f + ex2(sr));               // sigmoid (prescaled arg)
            float z = rcp(1.0f + ex2(sz));
            float u = fmaf(r, sn, pn[s]);                // 2log2e*(an + r*hn)
            float n = fmaf(-2.0f, rcp(1.0f + ex2(u)), 1.0f);   // tanh
            hj = fmaf(z, hj - n, n);                     // (1-z)*n + z*h
        }
        proj();          // projections for next bank (vmcnt wait lands here)
    }
    return hj;
}

// block = 128 threads = 2 waves. wave 0: bbox GRU, wave 1: flow GRU, for the
// same 8 batch elements. Lane mapping per wave: row = lane>>4 (4 DPP rows),
// parity = lane&1 → element e_local = row*2 + parity; unit j = (lane&15)>>1.
__global__ __launch_bounds__(128)
void gru_fused_kernel(const float* __restrict__ bbox, const float* __restrict__ flow,
                      const float* __restrict__ Wih_b, const float* __restrict__ Whh_b,
                      const float* __restrict__ bih_b, const float* __restrict__ bhh_b,
                      const float* __restrict__ Wih_f, const float* __restrict__ Whh_f,
                      const float* __restrict__ bih_f, const float* __restrict__ bhh_f,
                      float* __restrict__ out, int T)
{
    const int tid   = threadIdx.x;
    const int wave  = tid >> 6;
    const int lane  = tid & 63;
    const int eloc  = ((lane >> 4) << 1) | (lane & 1);   // 0..7
    const int j     = (lane & 15) >> 1;                  // hidden unit 0..7
    const int e     = blockIdx.x * 8 + eloc;

    __shared__ float sh[2][8][HDIM];

    float hT;
    if (wave == 0) {
        const float* xb = bbox + (size_t)e * T * 4;
        hT = gru_elem<4>(xb, 4, T, Wih_b, Whh_b, bih_b, bhh_b, j);
    } else {
        // flow[e, t, 2, 2, :] -> offset (e*T + t)*50 + 24, stride 50 floats
        const float* xf = flow + (size_t)e * T * 50 + 24;
        hT = gru_elem<2>(xf, 50, T, Wih_f, Whh_f, bih_f, bhh_f, j);
    }

    sh[wave][eloc][j] = hT;
    __syncthreads();
    if (wave == 0) {
        out[(size_t)e * HDIM + j] = 0.5f * (sh[0][eloc][j] + sh[1][eloc][j]);
    }
}

extern "C" void kernel_launch(void* const* d_in, const int* in_sizes, int n_in,
                              void* d_out, int out_size, void* d_ws, size_t ws_size,
                              hipStream_t stream) {
    const float* bbox  = (const float*)d_in[0];
    const float* flow  = (const float*)d_in[1];
    const float* Wih_b = (const float*)d_in[2];
    const float* Whh_b = (const float*)d_in[3];
    const float* bih_b = (const float*)d_in[4];
    const float* bhh_b = (const float*)d_in[5];
    const float* Wih_f = (const float*)d_in[6];
    const float* Whh_f = (const float*)d_in[7];
    const float* bih_f = (const float*)d_in[8];
    const float* bhh_f = (const float*)d_in[9];
    float* out = (float*)d_out;

    const int B = out_size / HDIM;            // 1024
    const int T = in_sizes[0] / (4 * B);      // 512

    dim3 grid(B / 8), block(128);
    gru_fused_kernel<<<grid, block, 0, stream>>>(
        bbox, flow, Wih_b, Whh_b, bih_b, bhh_b,
        Wih_f, Whh_f, bih_f, bhh_f, out, T);
}

// Round 4
// 68.618 us; speedup vs baseline: 3.6199x; 1.0406x over previous
//
#include <hip/hip_runtime.h>

#define HDIM 8

// ---- fast device math (v_exp_f32 / v_rcp_f32) ----
__device__ __forceinline__ float ex2(float x) {
#if __has_builtin(__builtin_amdgcn_exp2f)
    return __builtin_amdgcn_exp2f(x);
#else
    return exp2f(x);
#endif
}
__device__ __forceinline__ float rcp(float x) {
#if __has_builtin(__builtin_amdgcn_rcpf)
    return __builtin_amdgcn_rcpf(x);
#else
    return 1.0f / x;
#endif
}

// v_mov_b32_dpp row_ror:N (N immediate). 0x120+N = ROW_ROR DPP ctrl.
#define DPP_ROR(v, N)                                                        \
    __int_as_float(__builtin_amdgcn_update_dpp(                              \
        0, __float_as_int(v), 0x120 + (N), 0xF, 0xF, true))

// Distributed-h GRU, DPP edition (see round 3). Each 16-lane DPP row holds
// two elements interleaved (even/odd lanes); lane owns hidden unit
// j=(lane&15)>>1. row_ror:2m rotates by m within each 8-lane parity class —
// pure-VALU h all-gather. Rotation direction probed at runtime, folded into
// the weight gather.
// STRIDE (floats between timesteps) is a template constant so the 8-deep
// input prefetch compiles to one VGPR pointer + immediate offsets.
template <int IN, int STRIDE>
__device__ float gru_elem(const float* __restrict__ xbase, int T,
                          const float* __restrict__ Wih, const float* __restrict__ Whh,
                          const float* __restrict__ bih, const float* __restrict__ bhh,
                          int j)
{
    const float NL2E = -1.4426950408889634f;  // -log2(e)
    const float L2E2 =  2.8853900817779268f;  //  2*log2(e)

    // probe row_ror direction: partner of rotation 2 holds unit (j +- 1)&7
    float nbp = DPP_ROR((float)j, 2);
    const int dstep = (nbp == (float)((j + 1) & 7)) ? 1 : 7;

    // recurrent weights in rotation order: w[m] pairs with h_{(j + dstep*m)&7}
    float wr[8], wz[8], wn[8];
#pragma unroll
    for (int m = 0; m < 8; ++m) {
        const int k = (j + dstep * m) & 7;
        wr[m] = NL2E * Whh[(j     ) * HDIM + k];
        wz[m] = NL2E * Whh[(j +  8) * HDIM + k];
        wn[m] = L2E2 * Whh[(j + 16) * HDIM + k];
    }
    float uir[IN], uiz[IN], uin[IN];
#pragma unroll
    for (int i = 0; i < IN; ++i) {
        uir[i] = NL2E * Wih[(j     ) * IN + i];
        uiz[i] = NL2E * Wih[(j +  8) * IN + i];
        uin[i] = L2E2 * Wih[(j + 16) * IN + i];
    }
    const float br  = NL2E * (bih[j]     + bhh[j]);
    const float bz  = NL2E * (bih[j + 8] + bhh[j + 8]);
    const float bn  = L2E2 * bih[j + 16];
    const float bhn = L2E2 * bhh[j + 16];

    constexpr int U = 8;          // prefetch depth / unroll (T % U == 0 assumed)
    float xb[U][IN];              // staged inputs (loads in flight during steps)
    float pr[U], pz[U], pn[U];    // prescaled input projections

    auto loadx = [&](const float* px) {
#pragma unroll
        for (int s = 0; s < U; ++s) {
            const float* p = px + s * STRIDE;   // immediate offsets
            if constexpr (IN == 4) {
                float4 v = *reinterpret_cast<const float4*>(p);
                xb[s][0] = v.x; xb[s][1] = v.y; xb[s][2] = v.z; xb[s][3] = v.w;
            } else {
                float2 v = *reinterpret_cast<const float2*>(p);
                xb[s][0] = v.x; xb[s][1] = v.y;
            }
        }
    };
    auto proj = [&]() {
#pragma unroll
        for (int s = 0; s < U; ++s) {
            float a = br, b = bz, c = bn;
#pragma unroll
            for (int i = 0; i < IN; ++i) {
                a = fmaf(uir[i], xb[s][i], a);
                b = fmaf(uiz[i], xb[s][i], b);
                c = fmaf(uin[i], xb[s][i], c);
            }
            pr[s] = a; pz[s] = b; pn[s] = c;
        }
    };

    const float* px = xbase;
    loadx(px);                     // block 0
    proj();
    px += U * STRIDE;
    float hj = 0.0f;

    for (int t0 = 0; t0 < T; t0 += U) {
        if (t0 + U < T) {          // uniform branch; issue next block's loads
            loadx(px);
            px += U * STRIDE;
        }
#pragma unroll
        for (int s = 0; s < U; ++s) {
            // h all-gather: 7 DPP row-rotations (VALU only)
            const float hx0 = hj;
            const float hx1 = DPP_ROR(hj,  2);
            const float hx2 = DPP_ROR(hj,  4);
            const float hx3 = DPP_ROR(hj,  6);
            const float hx4 = DPP_ROR(hj,  8);
            const float hx5 = DPP_ROR(hj, 10);
            const float hx6 = DPP_ROR(hj, 12);
            const float hx7 = DPP_ROR(hj, 14);

            float ra = fmaf(wr[3], hx3, fmaf(wr[2], hx2, fmaf(wr[1], hx1, fmaf(wr[0], hx0, pr[s]))));
            float rb = fmaf(wr[7], hx7, fmaf(wr[6], hx6, fmaf(wr[5], hx5, wr[4] * hx4)));
            float za = fmaf(wz[3], hx3, fmaf(wz[2], hx2, fmaf(wz[1], hx1, fmaf(wz[0], hx0, pz[s]))));
            float zb = fmaf(wz[7], hx7, fmaf(wz[6], hx6, fmaf(wz[5], hx5, wz[4] * hx4)));
            float na = fmaf(wn[3], hx3, fmaf(wn[2], hx2, fmaf(wn[1], hx1, fmaf(wn[0], hx0, bhn))));
            float nb2 = fmaf(wn[7], hx7, fmaf(wn[6], hx6, fmaf(wn[5], hx5, wn[4] * hx4)));
            float sr = ra + rb;
            float sz = za + zb;
            float sn = na + nb2;

            float r = rcp(1.0f + ex2(sr));               // sigmoid (prescaled)
            float z = rcp(1.0f + ex2(sz));
            float u = fmaf(r, sn, pn[s]);                // 2log2e*(an + r*hn)
            float n = fmaf(-2.0f, rcp(1.0f + ex2(u)), 1.0f);   // tanh
            hj = fmaf(z, hj - n, n);                     // (1-z)*n + z*h
        }
        proj();        // consumes loads issued at loop top (8 steps of cover)
    }
    return hj;
}

// block = 128 threads = 2 waves. wave 0: bbox GRU, wave 1: flow GRU, same 8
// batch elements. launch_bounds(128,1): only 2 waves exist per block — give
// the register allocator the full budget so the prefetch pipeline survives.
__global__ __launch_bounds__(128, 1)
void gru_fused_kernel(const float* __restrict__ bbox, const float* __restrict__ flow,
                      const float* __restrict__ Wih_b, const float* __restrict__ Whh_b,
                      const float* __restrict__ bih_b, const float* __restrict__ bhh_b,
                      const float* __restrict__ Wih_f, const float* __restrict__ Whh_f,
                      const float* __restrict__ bih_f, const float* __restrict__ bhh_f,
                      float* __restrict__ out, int T)
{
    const int tid   = threadIdx.x;
    const int wave  = tid >> 6;
    const int lane  = tid & 63;
    const int eloc  = ((lane >> 4) << 1) | (lane & 1);   // 0..7
    const int j     = (lane & 15) >> 1;                  // hidden unit 0..7
    const int e     = blockIdx.x * 8 + eloc;

    __shared__ float sh[2][8][HDIM];

    float hT;
    if (wave == 0) {
        const float* xb = bbox + (size_t)e * T * 4;
        hT = gru_elem<4, 4>(xb, T, Wih_b, Whh_b, bih_b, bhh_b, j);
    } else {
        // flow[e, t, 2, 2, :] -> offset (e*T + t)*50 + 24, stride 50 floats
        const float* xf = flow + (size_t)e * T * 50 + 24;
        hT = gru_elem<2, 50>(xf, T, Wih_f, Whh_f, bih_f, bhh_f, j);
    }

    sh[wave][eloc][j] = hT;
    __syncthreads();
    if (wave == 0) {
        out[(size_t)e * HDIM + j] = 0.5f * (sh[0][eloc][j] + sh[1][eloc][j]);
    }
}

extern "C" void kernel_launch(void* const* d_in, const int* in_sizes, int n_in,
                              void* d_out, int out_size, void* d_ws, size_t ws_size,
                              hipStream_t stream) {
    const float* bbox  = (const float*)d_in[0];
    const float* flow  = (const float*)d_in[1];
    const float* Wih_b = (const float*)d_in[2];
    const float* Whh_b = (const float*)d_in[3];
    const float* bih_b = (const float*)d_in[4];
    const float* bhh_b = (const float*)d_in[5];
    const float* Wih_f = (const float*)d_in[6];
    const float* Whh_f = (const float*)d_in[7];
    const float* bih_f = (const float*)d_in[8];
    const float* bhh_f = (const float*)d_in[9];
    float* out = (float*)d_out;

    const int B = out_size / HDIM;            // 1024
    const int T = in_sizes[0] / (4 * B);      // 512

    dim3 grid(B / 8), block(128);
    gru_fused_kernel<<<grid, block, 0, stream>>>(
        bbox, flow, Wih_b, Whh_b, bih_b, bhh_b,
        Wih_f, Whh_f, bih_f, bhh_f, out, T);
}